// Round 3
// 1908.164 us; speedup vs baseline: 1.0272x; 1.0272x over previous
//
#include <hip/hip_runtime.h>
#include <math.h>

typedef float vf4 __attribute__((ext_vector_type(4)));
typedef _Float16 f16;
typedef _Float16 f16x8 __attribute__((ext_vector_type(8)));
typedef _Float16 f16x4 __attribute__((ext_vector_type(4)));
typedef float f32x4 __attribute__((ext_vector_type(4)));

static constexpr int Ncnt = 32768;
static constexpr int Kcb  = 4096;
static constexpr int Dim  = 256;

static constexpr float EPSf  = 1e-5f;
static constexpr float KEPSf = (float)(4096.0 * 1e-5);

// d_out float offsets (reference return order, flattened)
static constexpr size_t OQ  = 0;
static constexpr size_t OI  = (size_t)Ncnt * Dim;
static constexpr size_t OL  = OI + Ncnt;
static constexpr size_t OE  = OL + 1;
static constexpr size_t OCS = OE + (size_t)Kcb * Dim;
static constexpr size_t OW  = OCS + Kcb;
static constexpr size_t OU  = OW + (size_t)Kcb * Dim;
static constexpr size_t OS  = OU + Kcb;
static constexpr size_t OR  = OS + Kcb;

// ---------------------------------------------------------------------------
// numpy pairwise_sum over fl(p[i]*p[i]) for n=256 (bit-exact np.sum(x*x,1))
__device__ __forceinline__ float np_sq256(const float* __restrict__ p) {
  float tot[2];
  #pragma unroll
  for (int h = 0; h < 2; ++h) {
    const float* a = p + h * 128;
    float r[8];
    #pragma unroll
    for (int j = 0; j < 8; ++j) r[j] = __fmul_rn(a[j], a[j]);
    for (int i = 8; i < 128; i += 8)
      #pragma unroll
      for (int j = 0; j < 8; ++j) r[j] = __fadd_rn(r[j], __fmul_rn(a[i + j], a[i + j]));
    tot[h] = __fadd_rn(__fadd_rn(__fadd_rn(r[0], r[1]), __fadd_rn(r[2], r[3])),
                       __fadd_rn(__fadd_rn(r[4], r[5]), __fadd_rn(r[6], r[7])));
  }
  return __fadd_rn(tot[0], tot[1]);
}

__global__ void rowsq_np(const float* __restrict__ E, float* __restrict__ e2, int rows) {
  const int k = blockIdx.x * 256 + threadIdx.x;
  if (k < rows) e2[k] = np_sq256(E + (size_t)k * Dim);
}

// ---------------------------------------------------------------------------
// 2-limb f16 split with exact power-of-2 scaling:
//   t = v*scale (exact); hi = f16(t); lo = f16(t - hi)  (t - (f32)hi exact)
// layout: dst row = [hi(256) | lo(256)]
__global__ void split_rows(const float* __restrict__ src, f16* __restrict__ dst,
                           const float scale, const int rows)
{
  const int i   = blockIdx.x * 256 + threadIdx.x;
  const int row = i >> 6;
  const int d0  = (i & 63) * 4;
  if (row >= rows) return;
  const vf4 v = *(const vf4*)(src + (size_t)row * 256 + d0);
  f16x4 hi, lo;
  #pragma unroll
  for (int j = 0; j < 4; ++j) {
    const float t = __fmul_rn(v[j], scale);
    const f16 h   = (f16)t;
    const float r = __fsub_rn(t, (float)h);
    hi[j] = h;
    lo[j] = (f16)r;
  }
  *(f16x4*)(dst + (size_t)row * 512 + d0)       = hi;
  *(f16x4*)(dst + (size_t)row * 512 + 256 + d0) = lo;
}

// ---------------------------------------------------------------------------
// MFMA candidate pass. Grid: 2048 = 256 row-groups x 8 col-groups. Block =
// 128 rows x 512 cols (4 col-tiles of 128). Tile 128x128, 4 waves (2x2 of
// 64x64), BK=32. Virtual K = 768: hiX*hiE | loX*hiE | hiX*loE.
// Staging: global->reg->ds_write_b128 with 16B-chunk XOR swizzle
//   LDS[r][c] = global[r][c ^ ((r>>1)&3)]  (write-side swizzle, involution)
// Proxy t = e2[col] - two_scale*acc (x2 is row-constant: rank-equivalent).
// Per-thread-slot 2-deep (t,idx); 16-lane butterfly 2-deep merge; each
// wave-half (wc) writes its top-2 -> cand[row][cg][4]. Exact argmin is
// recomputed over candidates by recheck() with numpy-exact f32 semantics.
__global__ __launch_bounds__(256, 2) void mfma_argmin(
    const f16* __restrict__ Xs, const f16* __restrict__ Es,
    const float* __restrict__ e2, const float two_scale,
    int* __restrict__ cand)
{
  __shared__ __align__(16) f16 As[128 * 32];
  __shared__ __align__(16) f16 Bs[128 * 32];

  const int tid  = threadIdx.x;
  const int bid  = blockIdx.x;
  const int row0 = (bid >> 3) * 128;
  const int cg   = bid & 7;
  const int colbase = cg * 512;

  const int lane = tid & 63;
  const int wv   = tid >> 6;
  const int wr   = wv >> 1;
  const int wc   = wv & 1;
  const int lc   = lane & 15;
  const int kc   = lane >> 4;

  // staging map: row sr = tid>>1 (0..127), half sh = tid&1 (chunks 2sh,2sh+1)
  const int sr  = tid >> 1;
  const int sh  = tid & 1;
  const int ssw = (sr >> 1) & 3;
  f16* lA = As + sr * 32;
  f16* lB = Bs + sr * 32;
  const int w0 = ((2 * sh)     ^ ssw) * 8;
  const int w1 = ((2 * sh + 1) ^ ssw) * 8;

  const f16* aG = Xs + (size_t)(row0 + sr) * 512 + sh * 16;

  // frag-read swizzled k-slot (row = ..+lc; (row>>1)&3 == (lc>>1)&3)
  const int ks = (kc ^ ((lc >> 1) & 3)) * 8;

  float t1[16], t2[16];
  int   i1[16], i2[16];
  #pragma unroll
  for (int s = 0; s < 16; ++s) {
    t1[s] = INFINITY; t2[s] = INFINITY; i1[s] = 0x7fffffff; i2[s] = 0x7fffffff;
  }

  for (int ct = 0; ct < 4; ++ct) {
    const f16* bG = Es + (size_t)(colbase + ct * 128 + sr) * 512 + sh * 16;

    f32x4 acc[4][4];
    #pragma unroll
    for (int i = 0; i < 4; ++i)
      #pragma unroll
      for (int j = 0; j < 4; ++j)
        acc[i][j] = (f32x4){0.0f, 0.0f, 0.0f, 0.0f};

    f16x8 ra0 = *(const f16x8*)(aG);
    f16x8 ra1 = *(const f16x8*)(aG + 8);
    f16x8 rb0 = *(const f16x8*)(bG);
    f16x8 rb1 = *(const f16x8*)(bG + 8);

    for (int kk = 0; kk < 768; kk += 32) {
      *(f16x8*)(lA + w0) = ra0;
      *(f16x8*)(lA + w1) = ra1;
      *(f16x8*)(lB + w0) = rb0;
      *(f16x8*)(lB + w1) = rb1;
      __syncthreads();

      f16x8 af[4], bf[4];
      #pragma unroll
      for (int f = 0; f < 4; ++f) {
        af[f] = *(const f16x8*)(As + (wr * 64 + f * 16 + lc) * 32 + ks);
        bf[f] = *(const f16x8*)(Bs + (wc * 64 + f * 16 + lc) * 32 + ks);
      }

      if (kk + 32 < 768) {              // prefetch flies during the MFMAs
        const int kn = kk + 32;
        const int aC = (kn < 512) ? kn : (kn - 512);
        const int bC = (kn < 256) ? kn : (kn - 256);
        ra0 = *(const f16x8*)(aG + aC);
        ra1 = *(const f16x8*)(aG + aC + 8);
        rb0 = *(const f16x8*)(bG + bC);
        rb1 = *(const f16x8*)(bG + bC + 8);
      }

      #pragma unroll
      for (int fm = 0; fm < 4; ++fm)
        #pragma unroll
        for (int fn = 0; fn < 4; ++fn)
          acc[fm][fn] = __builtin_amdgcn_mfma_f32_16x16x32_f16(
              af[fm], bf[fn], acc[fm][fn], 0, 0, 0);

      __syncthreads();                  // frag reads done; LDS reusable
    }

    // fold this col-tile: 2-deep insert, cols strictly ascending over ct,fn
    #pragma unroll
    for (int fm = 0; fm < 4; ++fm) {
      #pragma unroll
      for (int j = 0; j < 4; ++j) {
        const int s = fm * 4 + j;
        #pragma unroll
        for (int fn = 0; fn < 4; ++fn) {
          const int col = colbase + ct * 128 + wc * 64 + fn * 16 + lc;
          const float t = __fsub_rn(e2[col], __fmul_rn(two_scale, acc[fm][fn][j]));
          if (t < t1[s]) {
            t2[s] = t1[s]; i2[s] = i1[s]; t1[s] = t; i1[s] = col;
          } else if (t < t2[s]) {
            t2[s] = t; i2[s] = col;
          }
        }
      }
    }
  }

  // 16-lane butterfly 2-deep merge within each kc row-group (lexicographic)
  #pragma unroll
  for (int s = 0; s < 16; ++s) {
    #pragma unroll
    for (int m = 1; m < 16; m <<= 1) {
      const float p1 = __shfl_xor(t1[s], m);
      const float p2 = __shfl_xor(t2[s], m);
      const int   q1 = __shfl_xor(i1[s], m);
      const int   q2 = __shfl_xor(i2[s], m);
      const bool pl = (p1 < t1[s]) || (p1 == t1[s] && q1 < i1[s]);
      float n1, n2; int m1, m2;
      if (pl) {
        n1 = p1; m1 = q1;
        const bool sl = (t1[s] < p2) || (t1[s] == p2 && i1[s] < q2);
        n2 = sl ? t1[s] : p2; m2 = sl ? i1[s] : q2;
      } else {
        n1 = t1[s]; m1 = i1[s];
        const bool sl = (p1 < t2[s]) || (p1 == t2[s] && q1 < i2[s]);
        n2 = sl ? p1 : t2[s]; m2 = sl ? q1 : i2[s];
      }
      t1[s] = n1; i1[s] = m1; t2[s] = n2; i2[s] = m2;
    }
  }

  // each wave-half writes its top-2 per owned row: cand[row][cg][wc*2+{0,1}]
  if (lc == 0) {
    #pragma unroll
    for (int fm = 0; fm < 4; ++fm)
      #pragma unroll
      for (int j = 0; j < 4; ++j) {
        const int s    = fm * 4 + j;
        const int rloc = wr * 64 + fm * 16 + kc * 4 + j;
        const size_t base = ((size_t)(row0 + rloc) * 8 + cg) * 4 + wc * 2;
        cand[base]     = i1[s];
        cand[base + 1] = i2[s];
      }
  }
}

// ---------------------------------------------------------------------------
// exact recheck: for each row, recompute numpy-exact f32 distance for the 32
// candidates and take lexicographic (s, k) min — identical arithmetic to the
// previously-passing VALU kernel (serial ascending-d fmaf chain, then
// s = fl(fl(x2 - fl(2*acc)) + e2[k])), numpy first-index tie semantics.
__global__ void recheck(const float* __restrict__ X, const float* __restrict__ x2g,
                        const float* __restrict__ Eref, const float* __restrict__ e2ref,
                        const int* __restrict__ cand, int* __restrict__ idxo)
{
  __shared__ float Xl[8][256];
  const int tid  = threadIdx.x;
  const int rg   = tid >> 5;            // row within block (8 rows/block)
  const int lr   = tid & 31;            // candidate lane
  const int row0 = blockIdx.x * 8;
  const int row  = row0 + rg;

  {
    const float* xp = X + (size_t)row * 256 + lr * 8;
    *(vf4*)(&Xl[rg][lr * 8])     = *(const vf4*)xp;
    *(vf4*)(&Xl[rg][lr * 8 + 4]) = *(const vf4*)(xp + 4);
  }
  __syncthreads();

  int k = cand[(size_t)row * 32 + lr];

  float acc = 0.0f;
  const float* ep = Eref + (size_t)k * 256;
  for (int d4 = 0; d4 < 64; ++d4) {
    const vf4 xv = *(const vf4*)(&Xl[rg][d4 * 4]);
    const vf4 ev = *(const vf4*)(ep + d4 * 4);
    acc = fmaf(xv[0], ev[0], acc);
    acc = fmaf(xv[1], ev[1], acc);
    acc = fmaf(xv[2], ev[2], acc);
    acc = fmaf(xv[3], ev[3], acc);
  }
  float s = __fadd_rn(__fsub_rn(x2g[row], __fmul_rn(2.0f, acc)), e2ref[k]);

  #pragma unroll
  for (int m = 1; m < 32; m <<= 1) {
    const float os = __shfl_xor(s, m);
    const int   ok = __shfl_xor(k, m);
    if (os < s || (os == s && ok < k)) { s = os; k = ok; }
  }
  if (lr == 0) idxo[row] = k;
}

// ----------------------- counts + dw atomics + loss (no OQ/OI writes) ------
__global__ void stats_cd(const float* __restrict__ X, const float* __restrict__ E,
                         const int* __restrict__ idx, float* __restrict__ counts,
                         float* __restrict__ dw, double* __restrict__ loss_acc)
{
  __shared__ double part[4];
  const int tid  = threadIdx.x;
  const int lane = tid & 63, w = tid >> 6;
  const int row  = blockIdx.x * 4 + w;
  const int k    = idx[row];
  const vf4 xv = ((const vf4*)X)[(size_t)row * 64 + lane];
  const vf4 qv = ((const vf4*)E)[(size_t)k * 64 + lane];
  const float d0 = xv[0]-qv[0], d1 = xv[1]-qv[1], d2 = xv[2]-qv[2], d3 = xv[3]-qv[3];
  double ps = (double)(d0*d0 + d1*d1 + d2*d2 + d3*d3);
  #pragma unroll
  for (int o = 32; o; o >>= 1) ps += __shfl_down(ps, o);
  #pragma unroll
  for (int j = 0; j < 4; ++j)
    atomicAdd(dw + (size_t)k * Dim + lane * 4 + j, xv[j]);
  if (lane == 0) {
    part[w] = ps;
    atomicAdd(counts + k, 1.0f);
  }
  __syncthreads();
  if (tid == 0) atomicAdd(loss_acc, part[0] + part[1] + part[2] + part[3]);
}

// quantized gather + index write, LAST (frees OQ region for Xs during argmins)
__global__ void gather_q(const float* __restrict__ E, const int* __restrict__ idx,
                         float* __restrict__ out)
{
  const int tid  = threadIdx.x;
  const int lane = tid & 63, w = tid >> 6;
  const int row  = blockIdx.x * 4 + w;
  const int k    = idx[row];
  ((vf4*)out)[(size_t)row * 64 + lane] = ((const vf4*)E)[(size_t)k * 64 + lane];
  if (lane == 0) out[OI + row] = (float)k;
}

// ------------------------------------------------- per-code EMA scalar updates
__global__ void cs_usage(const float* __restrict__ ecs, const float* __restrict__ usage,
                         const float* __restrict__ counts, float* __restrict__ out,
                         int* __restrict__ pos_cnt)
{
  __shared__ int si[256];
  const int tid = threadIdx.x;
  const int k   = blockIdx.x * 256 + tid;
  const float cnt = counts[k];
  const float ncs = __fadd_rn(__fmul_rn(ecs[k], 0.99f), __fmul_rn(0.01f, cnt));
  out[OCS + k] = ncs;
  const float nus = __fadd_rn(__fmul_rn(usage[k], 0.99f), __fmul_rn(0.01f, cnt));
  out[OU + k] = nus;
  si[tid] = (nus > 0.0f) ? 1 : 0;
  __syncthreads();
  for (int s = 128; s; s >>= 1) {
    if (tid < s) si[tid] += si[tid + s];
    __syncthreads();
  }
  if (tid == 0) atomicAdd(pos_cnt, si[0]);
}

// n = np.sum(new_cs), numpy pairwise over 4096
__global__ void n_np_kernel(const float* __restrict__ ncs, float* __restrict__ nf) {
  __shared__ float leaf[32];
  const int t = threadIdx.x;
  if (t < 32) {
    const float* a = ncs + t * 128;
    float r[8];
    #pragma unroll
    for (int j = 0; j < 8; ++j) r[j] = a[j];
    for (int i = 8; i < 128; i += 8)
      #pragma unroll
      for (int j = 0; j < 8; ++j) r[j] = __fadd_rn(r[j], a[i + j]);
    leaf[t] = __fadd_rn(__fadd_rn(__fadd_rn(r[0], r[1]), __fadd_rn(r[2], r[3])),
                        __fadd_rn(__fadd_rn(r[4], r[5]), __fadd_rn(r[6], r[7])));
  }
  __syncthreads();
  if (t == 0) {
    float v[32];
    #pragma unroll
    for (int i = 0; i < 32; ++i) v[i] = leaf[i];
    for (int n = 32; n > 1; n >>= 1)
      for (int i = 0; i < (n >> 1); ++i) v[i] = __fadd_rn(v[2 * i], v[2 * i + 1]);
    *nf = v[0];
  }
}

// new_ema_w (in place over dw accum) and pre-embedding (written to out[OE];
// all consumers of the pre-reset embedding run before finalize_k), numpy order
__global__ void emb_pre(const float* __restrict__ emaw, float* __restrict__ out,
                        const float* __restrict__ nf)
{
  const int k = blockIdx.x;
  const int d = threadIdx.x;
  const size_t o = (size_t)k * Dim + d;
  const float dwv = out[OW + o];
  const float w = __fadd_rn(__fmul_rn(emaw[o], 0.99f), __fmul_rn(0.01f, dwv));
  out[OW + o] = w;
  const float nv  = *nf;
  const float ncs = out[OCS + k];
  const float cs  = __fmul_rn(__fdiv_rn(__fadd_rn(ncs, EPSf), __fadd_rn(nv, KEPSf)), nv);
  out[OE + o] = __fdiv_rn(w, cs);
}

__global__ void used_scatter(const int* __restrict__ idx2, int* __restrict__ used) {
  const int i = blockIdx.x * 256 + threadIdx.x;
  used[idx2[i]] = 1;
}

__global__ void finalize_k(const float* __restrict__ X, const int* __restrict__ used,
                           const int* __restrict__ steps_in, const int* __restrict__ rnd,
                           float* __restrict__ out)
{
  const int k = blockIdx.x, d = threadIdx.x;
  const int u = used[k];
  const float st = u ? 0.0f : (float)steps_in[k] + 1.0f;
  const bool dead = st > 100.0f;
  if (dead) out[OE + (size_t)k * Dim + d] = X[(size_t)rnd[k] * Dim + d];
  if (d == 0) out[OS + k] = dead ? 0.0f : st;
}

__global__ void write_scalars(const double* __restrict__ loss_acc,
                              const int* __restrict__ pos_cnt, float* __restrict__ out)
{
  if (threadIdx.x == 0) {
    out[OL] = 0.25f * (float)(*loss_acc / (double)((size_t)Ncnt * Dim));
    out[OR] = (float)(*pos_cnt) / (float)Kcb;
  }
}

// ---------------------------------------------------------------------- launch
extern "C" void kernel_launch(void* const* d_in, const int* in_sizes, int n_in,
                              void* d_out, int out_size, void* d_ws, size_t ws_size,
                              hipStream_t stream)
{
  const float* X     = (const float*)d_in[0];
  const float* E     = (const float*)d_in[1];
  const float* ECS   = (const float*)d_in[2];
  const float* EMAW  = (const float*)d_in[3];
  const float* USAGE = (const float*)d_in[4];
  const int*   STEPS = (const int*)d_in[5];
  const int*   RND   = (const int*)d_in[6];
  float* out = (float*)d_out;

  float* wsf = (float*)d_ws;
  float*  counts   = wsf;                          // [4096]  zeroed
  int*    used     = (int*)(wsf + 4096);           // [4096]  zeroed
  double* loss_acc = (double*)(wsf + 8192);        //         zeroed
  float*  nf       = wsf + 8194;
  int*    pos_cnt  = (int*)(wsf + 8195);
  const size_t ZN  = 8200;                         // zero region, floats
  float* x2g  = wsf + 8320;                        // [32768]          -> 41088
  float* e2   = wsf + 41088;                       // [4096]           -> 45184
  float* e2p  = wsf + 45184;                       // [4096]           -> 49280
  int*   idx1 = (int*)(wsf + 49280);               // [32768]          -> 82048
  int*   idx2 = (int*)(wsf + 82048);               // [32768]          -> 114816
  f16*   Es   = (f16*)(wsf + 114816);              // 4096*512 f16 = 1048576 f -> 1163392
  int*   cand = (int*)(wsf + 1163392);             // 32768*32 ints    -> 2211968
  // pre-reset embedding lives directly in out[OE] (consumers run pre-reset).
  // Xs (32768x512 f16 = 32 MiB) parks exactly in the OQ output region;
  // gather_q rewrites OQ after the second argmin is done.
  f16*   Xsp  = (f16*)out;

  hipMemsetAsync(d_ws, 0, ZN * sizeof(float), stream);
  hipMemsetAsync(out + OW, 0, (size_t)Kcb * Dim * sizeof(float), stream); // dw accum

  rowsq_np     <<<Ncnt / 256, 256, 0, stream>>>(X, x2g, Ncnt);
  rowsq_np     <<<Kcb / 256,  256, 0, stream>>>(E, e2, Kcb);
  split_rows   <<<Ncnt / 4,   256, 0, stream>>>(X, Xsp, 64.0f, Ncnt);      // 2^6
  split_rows   <<<Kcb / 4,    256, 0, stream>>>(E, Es, 16777216.0f, Kcb);  // 2^24
  mfma_argmin  <<<2048,       256, 0, stream>>>(Xsp, Es, e2, 0x1p-29f, cand);
  recheck      <<<Ncnt / 8,   256, 0, stream>>>(X, x2g, E, e2, cand, idx1);
  stats_cd     <<<Ncnt / 4,   256, 0, stream>>>(X, E, idx1, counts, out + OW, loss_acc);
  cs_usage     <<<Kcb / 256,  256, 0, stream>>>(ECS, USAGE, counts, out, pos_cnt);
  n_np_kernel  <<<1,          64,  0, stream>>>(out + OCS, nf);
  emb_pre      <<<Kcb,        256, 0, stream>>>(EMAW, out, nf);
  rowsq_np     <<<Kcb / 256,  256, 0, stream>>>(out + OE, e2p, Kcb);
  split_rows   <<<Kcb / 4,    256, 0, stream>>>(out + OE, Es, 256.0f, Kcb); // 2^8
  mfma_argmin  <<<2048,       256, 0, stream>>>(Xsp, Es, e2p, 0x1p-13f, cand);
  recheck      <<<Ncnt / 8,   256, 0, stream>>>(X, x2g, out + OE, e2p, cand, idx2);
  used_scatter <<<Ncnt / 256, 256, 0, stream>>>(idx2, used);
  finalize_k   <<<Kcb,        256, 0, stream>>>(X, used, STEPS, RND, out);
  gather_q     <<<Ncnt / 4,   256, 0, stream>>>(E, idx1, out);
  write_scalars<<<1,          64,  0, stream>>>(loss_acc, pos_cnt, out);

  (void)in_sizes; (void)n_in; (void)out_size; (void)ws_size;
}